// Round 2
// baseline (27254.144 us; speedup 1.0000x reference)
//
#include <hip/hip_runtime.h>
#include <hip/hip_cooperative_groups.h>
#include <math.h>

namespace cg = cooperative_groups;

// RnnModelInterp persistent kernel. One cooperative launch; 199 steps inside
// with 2 grid.sync() per step.
//   Phase B: h1 = tanh(h0@Wih1 + Q1 + b1)   [g=0 half of threads]
//            R0 = h0@Whh0                    [g=1 half]
//   Phase C: WGs 0..127 : Q1 = h1@Whh1
//            WGs 128..255: heads+softmax+out+impute+h0' (2 rows each)
// ws layout (floats): h0[256*512] | h1[256*512] | Q1[256*512] | R0[256*512] | valc[256*64]

#define OFF_H1 131072
#define OFF_Q1 262144
#define OFF_R0 393216
#define OFF_VALC 524288

__device__ __forceinline__ bool nanf_bits(float v) {
  return (__float_as_uint(v) & 0x7fffffffu) > 0x7f800000u;
}

__device__ __forceinline__ void mk44(const float4 av[4], const float4 wv[4],
                                     float acc[4][4]) {
#pragma unroll
  for (int ri = 0; ri < 4; ++ri) {
    const float ax = av[ri].x, ay = av[ri].y, az = av[ri].z, aw = av[ri].w;
    acc[ri][0] += ax * wv[0].x + ay * wv[1].x + az * wv[2].x + aw * wv[3].x;
    acc[ri][1] += ax * wv[0].y + ay * wv[1].y + az * wv[2].y + aw * wv[3].y;
    acc[ri][2] += ax * wv[0].z + ay * wv[1].z + az * wv[2].z + aw * wv[3].z;
    acc[ri][3] += ax * wv[0].w + ay * wv[1].w + az * wv[2].w + aw * wv[3].w;
  }
}

// 4-row x 4-col micro tile over 64 ks. A rows stride 512, W rows stride 512.
__device__ __forceinline__ void gemm64(const float* __restrict__ Ap,
                                       const float* __restrict__ Wp,
                                       float acc[4][4]) {
  for (int k = 0; k < 64; k += 4) {
    float4 av[4], wv[4];
    av[0] = *(const float4*)(Ap + k);
    av[1] = *(const float4*)(Ap + 512 + k);
    av[2] = *(const float4*)(Ap + 1024 + k);
    av[3] = *(const float4*)(Ap + 1536 + k);
    wv[0] = *(const float4*)(Wp + (size_t)(k + 0) * 512);
    wv[1] = *(const float4*)(Wp + (size_t)(k + 1) * 512);
    wv[2] = *(const float4*)(Wp + (size_t)(k + 2) * 512);
    wv[3] = *(const float4*)(Wp + (size_t)(k + 3) * 512);
    mk44(av, wv, acc);
  }
}

__global__ __launch_bounds__(512) void rnn_all(
    const float* __restrict__ cat_seq, const float* __restrict__ val_seq,
    const float* __restrict__ Wih0, const float* __restrict__ Whh0,
    const float* __restrict__ b0v, const float* __restrict__ Wih1,
    const float* __restrict__ Whh1, const float* __restrict__ b1v,
    const float* __restrict__ Wc, const float* __restrict__ bcv,
    const float* __restrict__ Wm, const float* __restrict__ bmv,
    float* __restrict__ out, float* __restrict__ ws) {
  cg::grid_group grid = cg::this_grid();
  float* h0 = ws;
  float* h1 = ws + OFF_H1;
  float* Q1 = ws + OFF_Q1;
  float* R0 = ws + OFF_R0;
  float* valc = ws + OFF_VALC;
  const int w = blockIdx.x, tid = threadIdx.x;

  __shared__ float red[8704];   // k-split reduction, 17-padded
  __shared__ float h1s[2][512];
  __shared__ float xs[2][68];
  __shared__ float red2[512];
  __shared__ float redc[6];

  // ---- prologue: h0_1 = tanh(x0@Wih0 + b0); Q1 = 0; valc = val0. row = w ----
  {
    if (tid < 64) {
      float v = val_seq[(size_t)w * 64 + tid];
      valc[(size_t)w * 64 + tid] = v;
      xs[0][3 + tid] = v;
    } else if (tid < 67) {
      xs[0][tid - 64] = cat_seq[(size_t)w * 3 + (tid - 64)];
    }
    __syncthreads();
    float a = b0v[tid];
    for (int k = 0; k < 67; ++k) a += xs[0][k] * Wih0[(size_t)k * 512 + tid];
    h0[(size_t)w * 512 + tid] = tanhf(a);
    Q1[(size_t)w * 512 + tid] = 0.f;
  }
  grid.sync();

  for (int i = 0; i < 199; ++i) {
    // ================= PHASE B =================
    // tile 32 rows x 16 cols per WG, both GEMMs (g = tid>>8), 8-way K split.
    {
      const int g = tid >> 8;
      const int kq = (tid >> 5) & 7;
      const int pos = tid & 31;              // pr = pos>>2 (8), pc = pos&3 (4)
      const int r0 = (w >> 5) * 32, c0 = (w & 31) * 16;
      const int kb = kq * 64;
      const float* Ap = h0 + (size_t)(r0 + (pos >> 2) * 4) * 512 + kb;
      const float* Wp = (g ? Whh0 : Wih1) + (size_t)kb * 512 + c0 + (pos & 3) * 4;
      float acc[4][4] = {};
      gemm64(Ap, Wp, acc);
      float* rp = red + (g * 8 + kq) * 544 + pos * 17;
#pragma unroll
      for (int ri = 0; ri < 4; ++ri)
#pragma unroll
        for (int cj = 0; cj < 4; ++cj) rp[ri * 4 + cj] = acc[ri][cj];
      __syncthreads();
      {
        const int g2 = tid >> 8, t8 = tid & 255;
        const int opos = t8 >> 3, oe = (t8 * 2) & 15;  // oe even
        const int row = r0 + (opos >> 2) * 4 + (oe >> 2);
        const int col = c0 + (opos & 3) * 4 + (oe & 3);
        const float* rb = red + g2 * 4352 + opos * 17 + oe;
        float s0 = 0.f, s1 = 0.f;
#pragma unroll
        for (int q = 0; q < 8; ++q) { s0 += rb[q * 544]; s1 += rb[q * 544 + 1]; }
        if (g2 == 0) {
          const float2 qv = *(const float2*)(Q1 + (size_t)row * 512 + col);
          float2 o;
          o.x = tanhf(s0 + qv.x + b1v[col]);
          o.y = tanhf(s1 + qv.y + b1v[col + 1]);
          *(float2*)(h1 + (size_t)row * 512 + col) = o;
        } else {
          float2 o = {s0, s1};
          *(float2*)(R0 + (size_t)row * 512 + col) = o;
        }
      }
    }
    grid.sync();
    // ================= PHASE C =================
    if (w < 128) {
      // Q1 = h1 @ Whh1 ; tile 32x32, 8-way K split.
      const int kq = tid >> 6, pos = tid & 63;  // pr = pos>>3 (8), pc = pos&7 (8)
      const int r0 = (w >> 4) * 32, c0 = (w & 15) * 32;
      const int kb = kq * 64;
      const float* Ap = h1 + (size_t)(r0 + (pos >> 3) * 4) * 512 + kb;
      const float* Wp = Whh1 + (size_t)kb * 512 + c0 + (pos & 7) * 4;
      float acc[4][4] = {};
      gemm64(Ap, Wp, acc);
      float* rp = red + kq * 1088 + pos * 17;
#pragma unroll
      for (int ri = 0; ri < 4; ++ri)
#pragma unroll
        for (int cj = 0; cj < 4; ++cj) rp[ri * 4 + cj] = acc[ri][cj];
      __syncthreads();
      {
        const int opos = tid >> 3, oe = (tid * 2) & 15;
        const int row = r0 + (opos >> 3) * 4 + (oe >> 2);
        const int col = c0 + (opos & 7) * 4 + (oe & 3);
        const float* rb = red + opos * 17 + oe;
        float s0 = 0.f, s1 = 0.f;
#pragma unroll
        for (int q = 0; q < 8; ++q) { s0 += rb[q * 1088]; s1 += rb[q * 1088 + 1]; }
        float2 o = {s0, s1};
        *(float2*)(Q1 + (size_t)row * 512 + col) = o;
      }
    } else {
      // heads + softmax + out + impute + h0 update; rows row0, row0+1.
      const int row0 = (w - 128) * 2;
      if (tid < 256) {
        const int r = tid >> 7, q = tid & 127;
        *(float4*)&h1s[r][q * 4] =
            *(const float4*)(h1 + (size_t)(row0 + r) * 512 + q * 4);
      }
      __syncthreads();
      {  // o_val partials: m = col, r = row, ks = 4-way K split
        const int m = tid & 63, r = (tid >> 6) & 1, ks = tid >> 7;
        const float* hp = &h1s[r][ks * 128];
        const float* wp = Wm + (size_t)(ks * 128) * 64 + m;
        float a = 0.f;
        for (int k = 0; k < 128; ++k) a += hp[k] * wp[(size_t)k * 64];
        red2[(ks * 2 + r) * 64 + m] = a;
      }
      __syncthreads();
      if (tid < 128) {  // finalize o_val + impute val_next
        const int m = tid & 63, r = tid >> 6;
        float s = red2[r * 64 + m] + red2[(2 + r) * 64 + m] +
                  red2[(4 + r) * 64 + m] + red2[(6 + r) * 64 + m];
        float ov = s + bmv[m] + valc[(size_t)(row0 + r) * 64 + m];
        float raw = val_seq[(size_t)(i + 1) * 16384 + (size_t)(row0 + r) * 64 + m];
        float nv = nanf_bits(raw) ? ov : raw;
        valc[(size_t)(row0 + r) * 64 + m] = nv;
        xs[r][3 + m] = nv;
      } else {  // cat logits: waves 2..7 -> d = (r,j), shfl reduce
        const int l = tid - 128;
        const int d = l >> 6, lane = l & 63;
        const int r = d / 3, j = d % 3;
        float a = 0.f;
        const float* hp = &h1s[r][lane * 8];
        const float* wp = Wc + (size_t)(lane * 8) * 3 + j;
#pragma unroll
        for (int k = 0; k < 8; ++k) a += hp[k] * wp[k * 3];
        a += __shfl_down(a, 32);
        a += __shfl_down(a, 16);
        a += __shfl_down(a, 8);
        a += __shfl_down(a, 4);
        a += __shfl_down(a, 2);
        a += __shfl_down(a, 1);
        if (lane == 0) redc[d] = a + bcv[j];
      }
      __syncthreads();
      if (tid < 2) {  // softmax + out + impute cat
        const int r = tid;
        float l0 = redc[r * 3], l1 = redc[r * 3 + 1], l2 = redc[r * 3 + 2];
        float mx = fmaxf(l0, fmaxf(l1, l2));
        float e0 = expf(l0 - mx), e1 = expf(l1 - mx), e2 = expf(l2 - mx);
        float inv = 1.f / (e0 + e1 + e2);
        float p0 = e0 * inv, p1 = e1 * inv, p2 = e2 * inv;
        size_t ob = (size_t)i * 768 + (size_t)(row0 + r) * 3;
        out[ob] = p0; out[ob + 1] = p1; out[ob + 2] = p2;
        size_t cb = (size_t)(i + 1) * 768 + (size_t)(row0 + r) * 3;
        float c0_ = cat_seq[cb], c1_ = cat_seq[cb + 1], c2_ = cat_seq[cb + 2];
        xs[r][0] = nanf_bits(c0_) ? p0 : c0_;
        xs[r][1] = nanf_bits(c1_) ? p1 : c1_;
        xs[r][2] = nanf_bits(c2_) ? p2 : c2_;
      }
      __syncthreads();
      {  // h0' = tanh(x'@Wih0 + R0 + b0)
        const int r = tid >> 8, c = tid & 255;
        float a0 = b0v[c] + R0[(size_t)(row0 + r) * 512 + c];
        float a1 = b0v[c + 256] + R0[(size_t)(row0 + r) * 512 + c + 256];
        for (int k = 0; k < 67; ++k) {
          const float x = xs[r][k];
          a0 += x * Wih0[(size_t)k * 512 + c];
          a1 += x * Wih0[(size_t)k * 512 + c + 256];
        }
        h0[(size_t)(row0 + r) * 512 + c] = tanhf(a0);
        h0[(size_t)(row0 + r) * 512 + c + 256] = tanhf(a1);
      }
    }
    grid.sync();
  }
}

extern "C" void kernel_launch(void* const* d_in, const int* in_sizes, int n_in,
                              void* d_out, int out_size, void* d_ws, size_t ws_size,
                              hipStream_t stream) {
  const float* cat_seq = (const float*)d_in[0];
  const float* val_seq = (const float*)d_in[1];
  const float* Wih0 = (const float*)d_in[2];
  const float* Whh0 = (const float*)d_in[3];
  const float* b0 = (const float*)d_in[4];
  const float* Wih1 = (const float*)d_in[5];
  const float* Whh1 = (const float*)d_in[6];
  const float* b1 = (const float*)d_in[7];
  const float* Wc = (const float*)d_in[8];
  const float* bc = (const float*)d_in[9];
  const float* Wm = (const float*)d_in[10];
  const float* bm = (const float*)d_in[11];
  float* outp = (float*)d_out;
  float* wsp = (float*)d_ws;

  void* args[] = {(void*)&cat_seq, (void*)&val_seq, (void*)&Wih0, (void*)&Whh0,
                  (void*)&b0,      (void*)&Wih1,    (void*)&Whh1, (void*)&b1,
                  (void*)&Wc,      (void*)&bc,      (void*)&Wm,   (void*)&bm,
                  (void*)&outp,    (void*)&wsp};
  hipLaunchCooperativeKernel((void*)rnn_all, dim3(256), dim3(512), args, 0,
                             stream);
}

// Round 3
// 6033.688 us; speedup vs baseline: 4.5170x; 4.5170x over previous
//
#include <hip/hip_runtime.h>
#include <math.h>

// RnnModelInterp R3: 2 kernels/step multi-kernel graph (grid.sync banned — R2
// showed 68us/sync from agent-scope L2 invalidation on 8 XCDs).
// Recurrence restructured with R0/Q1 precompute:
//   S1: h1 = tanh(h0@Wih1 + Q1 + b1) ; R0 = h0@Whh0      (M=256,N=1024,K=512)
//   S2: Q1' = h1@Whh1 (256 WGs)  ||  role B (64 WGs, 4 rows each):
//       o_val/o_cat heads, softmax, out[t], impute seq[t+1], 
//       h0' = tanh(x'@Wih0 + R0 + b0)
// ws (floats): h0 | h1 | Q1 | R0 (256x512 each) | valc (256x64)

#define OFF_H1 131072
#define OFF_Q1 262144
#define OFF_R0 393216
#define OFF_VALC 524288

__device__ __forceinline__ bool nanf_bits(float v) {
  return (__float_as_uint(v) & 0x7fffffffu) > 0x7f800000u;
}

// ---------------- prologue: h0 = tanh(x0@Wih0 + b0); Q1 = 0; valc = val0 ----
__global__ __launch_bounds__(512) void prologue(
    const float* __restrict__ cat_seq, const float* __restrict__ val_seq,
    const float* __restrict__ Wih0, const float* __restrict__ b0,
    float* __restrict__ h0, float* __restrict__ Q1, float* __restrict__ valc) {
  __shared__ float xs[68];
  const int w = blockIdx.x, tid = threadIdx.x;
  if (tid < 64) {
    float v = val_seq[(size_t)w * 64 + tid];
    valc[(size_t)w * 64 + tid] = v;
    xs[3 + tid] = v;
  } else if (tid < 67) {
    xs[tid - 64] = cat_seq[(size_t)w * 3 + (tid - 64)];
  }
  __syncthreads();
  float a = b0[tid];
  for (int k = 0; k < 67; ++k) a += xs[k] * Wih0[(size_t)k * 512 + tid];
  h0[(size_t)w * 512 + tid] = tanhf(a);
  Q1[(size_t)w * 512 + tid] = 0.f;
}

// ---------------- S1: grid (32,16), 256 thr. ct<16 -> h1 half, else R0 half.
// BM=16, BN=32, K-split 4 (wave==kq). A in LDS (stride 516: 2-way max).
__global__ __launch_bounds__(256) void s1_kernel(
    const float* __restrict__ h0, const float* __restrict__ Q1,
    const float* __restrict__ Wih1, const float* __restrict__ Whh0,
    const float* __restrict__ b1, float* __restrict__ h1,
    float* __restrict__ R0) {
  __shared__ float smem[16 * 516 + 4 * 576];  // As | red[kq][16][36]
  float* As = smem;
  float* red = smem + 16 * 516;
  const int tid = threadIdx.x;
  const int ct = blockIdx.x;
  const int row0 = blockIdx.y * 16;
  const bool isH1 = ct < 16;
  const float* __restrict__ W = isH1 ? Wih1 : Whh0;
  const int cb = (isH1 ? ct : ct - 16) * 32;

  for (int idx = tid; idx < 2048; idx += 256) {
    const int r = idx >> 7, k4 = idx & 127;
    *(float4*)&As[r * 516 + k4 * 4] =
        *(const float4*)&h0[(size_t)(row0 + r) * 512 + k4 * 4];
  }
  __syncthreads();

  const int kq = tid >> 6, rp = (tid >> 3) & 7, cq = tid & 7;
  const int r0 = rp * 2;
  const int kb = kq * 128;
  const float* Wp = W + (size_t)kb * 512 + cb + cq * 4;
  const float* A0 = &As[r0 * 516 + kb];
  const float* A1 = A0 + 516;
  float4 acc0 = {0.f, 0.f, 0.f, 0.f}, acc1 = {0.f, 0.f, 0.f, 0.f};
  for (int k = 0; k < 128; k += 4) {
    const float4 a0 = *(const float4*)(A0 + k);
    const float4 a1 = *(const float4*)(A1 + k);
    const float* wk = Wp + (size_t)k * 512;
    const float4 w0 = *(const float4*)(wk);
    const float4 w1 = *(const float4*)(wk + 512);
    const float4 w2 = *(const float4*)(wk + 1024);
    const float4 w3 = *(const float4*)(wk + 1536);
    acc0.x += a0.x * w0.x + a0.y * w1.x + a0.z * w2.x + a0.w * w3.x;
    acc0.y += a0.x * w0.y + a0.y * w1.y + a0.z * w2.y + a0.w * w3.y;
    acc0.z += a0.x * w0.z + a0.y * w1.z + a0.z * w2.z + a0.w * w3.z;
    acc0.w += a0.x * w0.w + a0.y * w1.w + a0.z * w2.w + a0.w * w3.w;
    acc1.x += a1.x * w0.x + a1.y * w1.x + a1.z * w2.x + a1.w * w3.x;
    acc1.y += a1.x * w0.y + a1.y * w1.y + a1.z * w2.y + a1.w * w3.y;
    acc1.z += a1.x * w0.z + a1.y * w1.z + a1.z * w2.z + a1.w * w3.z;
    acc1.w += a1.x * w0.w + a1.y * w1.w + a1.z * w2.w + a1.w * w3.w;
  }
  {
    float* rw = &red[kq * 576 + r0 * 36 + cq * 4];
    *(float4*)rw = acc0;
    *(float4*)(rw + 36) = acc1;
  }
  __syncthreads();
  {
    const int o = tid * 2;
    const int rr = o >> 5, cc = o & 31;
    const float* rb = &red[rr * 36 + cc];
    const float sx = rb[0] + rb[576] + rb[1152] + rb[1728];
    const float sy = rb[1] + rb[577] + rb[1153] + rb[1729];
    const int col = cb + cc;
    if (isH1) {
      const float2 qv = *(const float2*)&Q1[(size_t)(row0 + rr) * 512 + col];
      float2 o2;
      o2.x = tanhf(sx + qv.x + b1[col]);
      o2.y = tanhf(sy + qv.y + b1[col + 1]);
      *(float2*)&h1[(size_t)(row0 + rr) * 512 + col] = o2;
    } else {
      float2 o2 = {sx, sy};
      *(float2*)&R0[(size_t)(row0 + rr) * 512 + col] = o2;
    }
  }
}

// ---------------- S2: grid 320, 256 thr.
// bid<256: Q1' = h1@Whh1 (BM=16,BN=32 tile like S1). bid>=256: role B.
__global__ __launch_bounds__(256) void s2_kernel(
    const float* __restrict__ h1, const float* __restrict__ R0,
    const float* __restrict__ Wih0, const float* __restrict__ b0,
    const float* __restrict__ Whh1, const float* __restrict__ Wc,
    const float* __restrict__ bc, const float* __restrict__ Wm,
    const float* __restrict__ bm, const float* __restrict__ cat_seq,
    const float* __restrict__ val_seq, float* __restrict__ h0,
    float* __restrict__ Q1, float* __restrict__ valc, float* __restrict__ out,
    int t) {
  __shared__ float smem[16 * 516 + 4 * 576];
  const int tid = threadIdx.x;
  if (blockIdx.x < 256) {
    float* As = smem;
    float* red = smem + 16 * 516;
    const int rt = blockIdx.x >> 4, ct = blockIdx.x & 15;
    const int row0 = rt * 16, cb = ct * 32;
    for (int idx = tid; idx < 2048; idx += 256) {
      const int r = idx >> 7, k4 = idx & 127;
      *(float4*)&As[r * 516 + k4 * 4] =
          *(const float4*)&h1[(size_t)(row0 + r) * 512 + k4 * 4];
    }
    __syncthreads();
    const int kq = tid >> 6, rp = (tid >> 3) & 7, cq = tid & 7;
    const int r0 = rp * 2;
    const int kb = kq * 128;
    const float* Wp = Whh1 + (size_t)kb * 512 + cb + cq * 4;
    const float* A0 = &As[r0 * 516 + kb];
    const float* A1 = A0 + 516;
    float4 acc0 = {0.f, 0.f, 0.f, 0.f}, acc1 = {0.f, 0.f, 0.f, 0.f};
    for (int k = 0; k < 128; k += 4) {
      const float4 a0 = *(const float4*)(A0 + k);
      const float4 a1 = *(const float4*)(A1 + k);
      const float* wk = Wp + (size_t)k * 512;
      const float4 w0 = *(const float4*)(wk);
      const float4 w1 = *(const float4*)(wk + 512);
      const float4 w2 = *(const float4*)(wk + 1024);
      const float4 w3 = *(const float4*)(wk + 1536);
      acc0.x += a0.x * w0.x + a0.y * w1.x + a0.z * w2.x + a0.w * w3.x;
      acc0.y += a0.x * w0.y + a0.y * w1.y + a0.z * w2.y + a0.w * w3.y;
      acc0.z += a0.x * w0.z + a0.y * w1.z + a0.z * w2.z + a0.w * w3.z;
      acc0.w += a0.x * w0.w + a0.y * w1.w + a0.z * w2.w + a0.w * w3.w;
      acc1.x += a1.x * w0.x + a1.y * w1.x + a1.z * w2.x + a1.w * w3.x;
      acc1.y += a1.x * w0.y + a1.y * w1.y + a1.z * w2.y + a1.w * w3.y;
      acc1.z += a1.x * w0.z + a1.y * w1.z + a1.z * w2.z + a1.w * w3.z;
      acc1.w += a1.x * w0.w + a1.y * w1.w + a1.z * w2.w + a1.w * w3.w;
    }
    {
      float* rw = &red[kq * 576 + r0 * 36 + cq * 4];
      *(float4*)rw = acc0;
      *(float4*)(rw + 36) = acc1;
    }
    __syncthreads();
    {
      const int o = tid * 2;
      const int rr = o >> 5, cc = o & 31;
      const float* rb = &red[rr * 36 + cc];
      float2 o2;
      o2.x = rb[0] + rb[576] + rb[1152] + rb[1728];
      o2.y = rb[1] + rb[577] + rb[1153] + rb[1729];
      *(float2*)&Q1[(size_t)(row0 + rr) * 512 + cb + cc] = o2;
    }
  } else {
    // ---- role B: rows row0..row0+3 ----
    float* hs = smem;               // 4*516
    float* xsr = smem + 2064;       // 4*68
    float* red2 = smem + 2336;      // [ks][r][64] = 1024
    float* lg = smem + 3360;        // 12
    const int row0 = (blockIdx.x - 256) * 4;
    for (int idx = tid; idx < 512; idx += 256) {
      const int r = idx >> 7, k4 = idx & 127;
      *(float4*)&hs[r * 516 + k4 * 4] =
          *(const float4*)&h1[(size_t)(row0 + r) * 512 + k4 * 4];
    }
    __syncthreads();
    {  // o_val partials: ks = wave, r, qc (16 col-quads)
      const int ks = tid >> 6, r = (tid >> 4) & 3, qc = tid & 15;
      const int kb = ks * 128;
      const float* hp = &hs[r * 516 + kb];
      const float* wp = Wm + (size_t)kb * 64 + qc * 4;
      float4 a = {0.f, 0.f, 0.f, 0.f};
      for (int k = 0; k < 128; k += 4) {
        const float4 hv = *(const float4*)(hp + k);
        const float* w = wp + (size_t)k * 64;
        const float4 w0 = *(const float4*)(w);
        const float4 w1 = *(const float4*)(w + 64);
        const float4 w2 = *(const float4*)(w + 128);
        const float4 w3 = *(const float4*)(w + 192);
        a.x += hv.x * w0.x + hv.y * w1.x + hv.z * w2.x + hv.w * w3.x;
        a.y += hv.x * w0.y + hv.y * w1.y + hv.z * w2.y + hv.w * w3.y;
        a.z += hv.x * w0.z + hv.y * w1.z + hv.z * w2.z + hv.w * w3.z;
        a.w += hv.x * w0.w + hv.y * w1.w + hv.z * w2.w + hv.w * w3.w;
      }
      *(float4*)&red2[ks * 256 + r * 64 + qc * 4] = a;
    }
    __syncthreads();
    {  // finalize o_val + impute val_next
      const int r = tid >> 6, m = tid & 63;
      const float s = red2[r * 64 + m] + red2[256 + r * 64 + m] +
                      red2[512 + r * 64 + m] + red2[768 + r * 64 + m];
      const float ov = s + bm[m] + valc[(size_t)(row0 + r) * 64 + m];
      const float raw =
          val_seq[(size_t)(t + 1) * 16384 + (size_t)(row0 + r) * 64 + m];
      const float nv = nanf_bits(raw) ? ov : raw;
      valc[(size_t)(row0 + r) * 64 + m] = nv;
      xsr[r * 68 + 3 + m] = nv;
    }
    {  // cat logits: wave r, lane covers 8 ks
      const int r = tid >> 6, lane = tid & 63;
      float a0 = 0.f, a1 = 0.f, a2 = 0.f;
      const float* hp = &hs[r * 516 + lane * 8];
      const float* wp = Wc + (size_t)lane * 24;
#pragma unroll
      for (int kk = 0; kk < 8; ++kk) {
        const float h = hp[kk];
        a0 += h * wp[kk * 3 + 0];
        a1 += h * wp[kk * 3 + 1];
        a2 += h * wp[kk * 3 + 2];
      }
#pragma unroll
      for (int off = 32; off >= 1; off >>= 1) {
        a0 += __shfl_down(a0, off);
        a1 += __shfl_down(a1, off);
        a2 += __shfl_down(a2, off);
      }
      if (lane == 0) {
        lg[r * 3 + 0] = a0 + bc[0];
        lg[r * 3 + 1] = a1 + bc[1];
        lg[r * 3 + 2] = a2 + bc[2];
      }
    }
    __syncthreads();
    if (tid < 4) {  // softmax + out + impute cat
      const int r = tid;
      const float l0 = lg[r * 3], l1 = lg[r * 3 + 1], l2 = lg[r * 3 + 2];
      const float mx = fmaxf(l0, fmaxf(l1, l2));
      const float e0 = expf(l0 - mx), e1 = expf(l1 - mx), e2 = expf(l2 - mx);
      const float inv = 1.f / (e0 + e1 + e2);
      const float p0 = e0 * inv, p1 = e1 * inv, p2 = e2 * inv;
      const size_t ob = (size_t)t * 768 + (size_t)(row0 + r) * 3;
      out[ob] = p0; out[ob + 1] = p1; out[ob + 2] = p2;
      const size_t cbx = (size_t)(t + 1) * 768 + (size_t)(row0 + r) * 3;
      const float c0 = cat_seq[cbx], c1 = cat_seq[cbx + 1],
                  c2 = cat_seq[cbx + 2];
      xsr[r * 68 + 0] = nanf_bits(c0) ? p0 : c0;
      xsr[r * 68 + 1] = nanf_bits(c1) ? p1 : c1;
      xsr[r * 68 + 2] = nanf_bits(c2) ? p2 : c2;
    }
    __syncthreads();
    {  // h0' = tanh(x'@Wih0 + R0 + b0)
      const int c4 = (tid & 127) * 4;
      const int rh = tid >> 7;
#pragma unroll
      for (int rw = 0; rw < 2; ++rw) {
        const int r = rh * 2 + rw;
        float4 acc = *(const float4*)&R0[(size_t)(row0 + r) * 512 + c4];
        const float4 bv = *(const float4*)&b0[c4];
        acc.x += bv.x; acc.y += bv.y; acc.z += bv.z; acc.w += bv.w;
        for (int k = 0; k < 67; ++k) {
          const float x = xsr[r * 68 + k];
          const float4 w = *(const float4*)&Wih0[(size_t)k * 512 + c4];
          acc.x += x * w.x; acc.y += x * w.y;
          acc.z += x * w.z; acc.w += x * w.w;
        }
        float4 o4;
        o4.x = tanhf(acc.x); o4.y = tanhf(acc.y);
        o4.z = tanhf(acc.z); o4.w = tanhf(acc.w);
        *(float4*)&h0[(size_t)(row0 + r) * 512 + c4] = o4;
      }
    }
  }
}

extern "C" void kernel_launch(void* const* d_in, const int* in_sizes, int n_in,
                              void* d_out, int out_size, void* d_ws, size_t ws_size,
                              hipStream_t stream) {
  const float* cat_seq = (const float*)d_in[0];
  const float* val_seq = (const float*)d_in[1];
  const float* Wih0 = (const float*)d_in[2];
  const float* Whh0 = (const float*)d_in[3];
  const float* b0 = (const float*)d_in[4];
  const float* Wih1 = (const float*)d_in[5];
  const float* Whh1 = (const float*)d_in[6];
  const float* b1 = (const float*)d_in[7];
  const float* Wc = (const float*)d_in[8];
  const float* bc = (const float*)d_in[9];
  const float* Wm = (const float*)d_in[10];
  const float* bm = (const float*)d_in[11];
  float* ws = (float*)d_ws;
  float* h0 = ws;
  float* h1 = ws + OFF_H1;
  float* Q1 = ws + OFF_Q1;
  float* R0 = ws + OFF_R0;
  float* valc = ws + OFF_VALC;
  float* out = (float*)d_out;

  hipLaunchKernelGGL(prologue, dim3(256), dim3(512), 0, stream,
                     cat_seq, val_seq, Wih0, b0, h0, Q1, valc);
  for (int t = 0; t < 199; ++t) {
    hipLaunchKernelGGL(s1_kernel, dim3(32, 16), dim3(256), 0, stream,
                       h0, Q1, Wih1, Whh0, b1, h1, R0);
    hipLaunchKernelGGL(s2_kernel, dim3(320), dim3(256), 0, stream,
                       h1, R0, Wih0, b0, Whh1, Wc, bc, Wm, bm,
                       cat_seq, val_seq, h0, Q1, valc, out, t);
  }
}